// Round 15
// baseline (1368.191 us; speedup 1.0000x reference)
//
#include <hip/hip_runtime.h>
#include <hip/hip_bf16.h>
#include <stdint.h>

#define BATCH 64
#define SLEN 128
#define TLEN 128
#define ENCD 512
#define DECD 512
#define EMBD 256
#define VOC  8000
#define HE   20
#define KX   1280      // EMB + DEC + ENC
#define NP2  8192      // VOC padded to 32*256

typedef __attribute__((ext_vector_type(8))) short short8;
typedef __attribute__((ext_vector_type(8))) _Float16 half8v;
typedef __attribute__((ext_vector_type(4))) float f32x4;
typedef _Float16 h2 __attribute__((ext_vector_type(2)));

// ---------- helpers ----------
__device__ inline unsigned short f2bf(float f) {
  union { float f; uint32_t u; } v; v.f = f;
  uint32_t r = v.u + 0x7fff + ((v.u >> 16) & 1);
  return (unsigned short)(r >> 16);
}
__device__ inline unsigned short f16bits(float f) {
  union { _Float16 h; unsigned short u; } c; c.h = (_Float16)f; return c.u;
}
__device__ inline uint32_t pkh2(float a, float b) {
  union { h2 h; uint32_t u; } v;
  v.h = h2{(_Float16)a, (_Float16)b};
  return v.u;
}
__device__ inline float fdot2(uint32_t a, uint32_t b, float c) {
#if __has_builtin(__builtin_amdgcn_fdot2)
  union { uint32_t u; h2 h; } x, y; x.u = a; y.u = b;
  return __builtin_amdgcn_fdot2(x.h, y.h, c, false);
#else
  union { uint32_t u; h2 h; } x, y; x.u = a; y.u = b;
  return c + (float)x.h[0] * (float)y.h[0] + (float)x.h[1] * (float)y.h[1];
#endif
}
__device__ inline float eluf(float x) { return x > 0.f ? x : (expf(x) - 1.f); }

typedef const __attribute__((address_space(1))) unsigned int* gptr_t;
typedef __attribute__((address_space(3))) unsigned int* lptr_t;
__device__ inline void gload16(const void* g, void* l) {
  __builtin_amdgcn_global_load_lds((gptr_t)g, (lptr_t)l, 16, 0, 0);
}

// ---------- k_pre1: merged k_lc / k_ench / k_e1 ----------
__global__ __launch_bounds__(256) void k_pre1(const int* __restrict__ ro,
                                              const float* __restrict__ emb,
                                              unsigned short* __restrict__ X,
                                              const float* __restrict__ enc,
                                              unsigned short* __restrict__ ench,
                                              const float* __restrict__ We1,
                                              float* __restrict__ E1) {
  __shared__ float rowbuf[4][ENCD];
  __shared__ float part[4][HE][2];
  int bid = blockIdx.x, tid = threadIdx.x;
  if (bid < 8192) {
    int r = bid;
    int t = r >> 6, b = r & 63;
    int lc = (t == 0) ? 0 : ro[b * TLEN + t - 1];
    lc = ((lc % VOC) + VOC) % VOC;
    X[(size_t)r * KX + tid] = f2bf(emb[(size_t)lc * EMBD + tid]);
  } else if (bid < 12288) {
    int i = ((bid - 8192) * 256 + tid) * 4;
    float4 v = *(const float4*)(enc + i);
    ushort4 o = { f16bits(v.x), f16bits(v.y), f16bits(v.z), f16bits(v.w) };
    *(ushort4*)(ench + i) = o;
  } else {
    int r0 = (bid - 12288) * 4;
    for (int i = tid; i < 4 * ENCD; i += 256) {
      int rl = i >> 9, e = i & 511;
      rowbuf[rl][e] = enc[(size_t)(r0 + rl) * ENCD + e];
    }
    __syncthreads();
    if (tid < 160) {
      int kg = tid / 80, rem = tid % 80, rl = rem / 20, h = rem % 20;
      float acc = 0.f;
      for (int k = kg * 256; k < kg * 256 + 256; ++k)
        acc += rowbuf[rl][k] * We1[k * HE + h];
      part[rl][h][kg] = acc;
    }
    __syncthreads();
    if (tid < 80) {
      int rl = tid / 20, h = tid % 20;
      int r = r0 + rl, bb = r >> 7, ss = r & 127;
      E1[((size_t)bb * HE + h) * SLEN + ss] = part[rl][h][0] + part[rl][h][1];
    }
  }
}

// ---------- k_pre2: merged k_tr_w(WembT) / k_tr_w(WctxT) / k_prep_wr ----------
__global__ __launch_bounds__(256) void k_pre2(const float* __restrict__ Wr,
                                              unsigned short* __restrict__ WembT,
                                              unsigned short* __restrict__ WctxT,
                                              unsigned short* __restrict__ W2) {
  __shared__ float tile[64][65];
  int bid = blockIdx.x, tid = threadIdx.x;
  if (bid < 96) {
    int k0, KN, fmt, bx, by;
    unsigned short* dst;
    if (bid < 32) { k0 = 0;   KN = 256; fmt = 1; bx = bid & 7; by = bid >> 3; dst = WembT; }
    else          { int id2 = bid - 32; k0 = 768; KN = 512; fmt = 0; bx = id2 & 7; by = id2 >> 3; dst = WctxT; }
    int n0 = bx * 64, kt = by * 64;
    for (int i = tid; i < 4096; i += 256) {
      int kk = i >> 6, nn = i & 63;
      tile[kk][nn] = Wr[(size_t)(k0 + kt + kk) * 512 + n0 + nn];
    }
    __syncthreads();
    for (int i = tid; i < 4096; i += 256) {
      int nn = i >> 6, kk = i & 63;
      float v = tile[kk][nn];
      dst[(size_t)(n0 + nn) * KN + kt + kk] = fmt ? f2bf(v) : f16bits(v);
    }
  } else {
    int i = (bid - 96) * 256 + tid;
    int n = i & 511;
    int j = (i >> 9) & 7;
    int kc = (i >> 12) & 31;
    int h = (i >> 17) & 1;
    int k = h * 256 + kc * 8 + j;
    W2[(((size_t)(h * 32 + kc) * 512) + n) * 8 + j] = f16bits(Wr[(size_t)(256 + k) * 512 + n]);
  }
}

// ---------- k_wh: wout f32 [8192][128] -> f16 ----------
__global__ __launch_bounds__(256) void k_wh(const float* __restrict__ wout,
                                            unsigned short* __restrict__ wh) {
  int i = (blockIdx.x * 256 + threadIdx.x) * 4;
  float4 v = *(const float4*)(wout + i);
  ushort4 o = { f16bits(v.x), f16bits(v.y), f16bits(v.z), f16bits(v.w) };
  *(ushort4*)(wh + i) = o;
}

// ---------- gs_body<MODE>: 128x128xK MFMA GEMM body ----------
#define BM 128
#define BN 128
#define BK 64

template<int MODE>
__device__ __forceinline__ void gs_body(
    unsigned short* Asd, unsigned short* Bsd,
    const unsigned short* __restrict__ A,
    const unsigned short* __restrict__ B,
    const float* __restrict__ bias,
    unsigned short* __restrict__ Cout,
    int bx, int by, int tid)
{
  constexpr int As = (MODE == 0) ? KX : (MODE == 1 ? 512 : 128);
  constexpr int Bs = (MODE == 0) ? 256 : (MODE == 1 ? 512 : 128);
  constexpr int KT = (MODE == 0) ? 4 : (MODE == 1 ? 8 : 2);
  int wid = tid >> 6, lane = tid & 63;
  int wr = wid >> 1, wc = wid & 1;

  f32x4 acc[4][4];
  for (int i = 0; i < 4; ++i)
    for (int j = 0; j < 4; ++j) acc[i][j] = (f32x4)0.f;

  const unsigned short* Abase = A + (size_t)by * BM * As;
  const unsigned short* Bbase = B + (size_t)bx * BN * Bs + (MODE == 2 ? (size_t)by * 512 * 128 : 0);

  for (int kt = 0; kt < KT; ++kt) {
    for (int j = 0; j < 4; ++j) {
      int c = tid + j * 256;
      int r = c >> 3, c16 = c & 7;
      int sk = c16 ^ (r & 7);
      gload16(Abase + (size_t)r * As + kt * BK + sk * 8, (char*)Asd + c * 16);
      gload16(Bbase + (size_t)r * Bs + kt * BK + sk * 8, (char*)Bsd + c * 16);
    }
    __syncthreads();
    for (int ks = 0; ks < 2; ++ks) {
      short8 af[4], bf[4];
      int kc = ks * 4 + (lane >> 4);
      for (int i = 0; i < 4; ++i) {
        int r = wr * 64 + i * 16 + (lane & 15);
        af[i] = *(const short8*)((const char*)Asd + r * 128 + ((kc ^ (r & 7)) * 16));
      }
      for (int j = 0; j < 4; ++j) {
        int r = wc * 64 + j * 16 + (lane & 15);
        bf[j] = *(const short8*)((const char*)Bsd + r * 128 + ((kc ^ (r & 7)) * 16));
      }
      for (int i = 0; i < 4; ++i)
        for (int j = 0; j < 4; ++j) {
          if constexpr (MODE == 0)
            acc[i][j] = __builtin_amdgcn_mfma_f32_16x16x32_bf16(af[i], bf[j], acc[i][j], 0, 0, 0);
          else
            acc[i][j] = __builtin_amdgcn_mfma_f32_16x16x32_f16(
                __builtin_bit_cast(half8v, af[i]), __builtin_bit_cast(half8v, bf[j]), acc[i][j], 0, 0, 0);
        }
    }
    __syncthreads();
  }

  int rl = lane >> 4, cl = lane & 15;
  for (int j = 0; j < 4; ++j) {
    int gn = bx * BN + wc * 64 + j * 16 + cl;
    for (int i = 0; i < 4; ++i) {
      for (int q = 0; q < 4; ++q) {
        int gm = by * BM + wr * 64 + i * 16 + rl * 4 + q;
        float v = acc[i][j][q];
        if constexpr (MODE == 0) {
          Cout[(size_t)gm * 512 + gn] = f16bits(v + bias[gn]);
        } else if constexpr (MODE == 1) {
          int bb = gm >> 7, s = gm & 127;
          Cout[(((size_t)(bb * 16 + (s >> 3)) * 512) + gn) * 8 + (s & 7)] = f16bits(v);
        } else {
          int tt = gm & 127, bb = gm >> 7;
          Cout[((size_t)tt * 64 + bb) * KX + 768 + gn] = f2bf(v);
        }
      }
    }
  }
}

// ---------- k_gs01: MODE0 (z=0) and MODE1 (z=1) in one launch ----------
__global__ __launch_bounds__(256) void k_gs01(
    const unsigned short* __restrict__ X,
    const unsigned short* __restrict__ WembT,
    const unsigned short* __restrict__ ench,
    const unsigned short* __restrict__ WctxT,
    const float* __restrict__ brnn,
    unsigned short* __restrict__ Remb,
    unsigned short* __restrict__ encW2)
{
  __shared__ __align__(16) unsigned short Asd[BM * BK];
  __shared__ __align__(16) unsigned short Bsd[BN * BK];
  if (blockIdx.z == 0)
    gs_body<0>(Asd, Bsd, X, WembT, brnn, Remb, blockIdx.x, blockIdx.y, threadIdx.x);
  else
    gs_body<1>(Asd, Bsd, ench, WctxT, brnn, encW2, blockIdx.x, blockIdx.y, threadIdx.x);
}

// ---------- k_gs2: MODE2 (ctx fill) ----------
__global__ __launch_bounds__(256) void k_gs2(
    const unsigned short* __restrict__ wh,
    const unsigned short* __restrict__ encTh,
    const float* __restrict__ brnn,
    unsigned short* __restrict__ X)
{
  __shared__ __align__(16) unsigned short Asd[BM * BK];
  __shared__ __align__(16) unsigned short Bsd[BN * BK];
  gs_body<2>(Asd, Bsd, wh, encTh, brnn, X, blockIdx.x, blockIdx.y, threadIdx.x);
}

// ---------- k_recur: r10 recurrence + W2-group-0 register cache + transposes ----------
// blocks 64..703 : W_out -> WoT [8192][1280] bf16 (zero-pad, 4 tiles each)
// blocks 704..959: enc -> encTh [b][e][s] f16 (4 tiles each)
#define STREAM4(PH) { \
  float a0 = 0, a1 = 0, a2 = 0, a3 = 0; \
  uint4 cb[8], nb[8]; \
  _Pragma("unroll") \
  for (int j = 0; j < 8; ++j) cb[j] = Wp[(size_t)j * 512]; \
  for (int blk = 0; blk < 4; ++blk) { \
    if (blk + 1 < 4) { \
      _Pragma("unroll") \
      for (int j = 0; j < 8; ++j) nb[j] = Wp[(size_t)((blk + 1) * 8 + j) * 512]; \
    } \
    _Pragma("unroll") \
    for (int j = 0; j < 8; ++j) { \
      uint4 wv = cb[j]; uint4 xv = hp4[hbase + blk * 8 + j]; \
      a0 = fdot2(wv.x, xv.x, a0); a1 = fdot2(wv.y, xv.y, a1); \
      a2 = fdot2(wv.z, xv.z, a2); a3 = fdot2(wv.w, xv.w, a3); \
    } \
    _Pragma("unroll") \
    for (int j = 0; j < 8; ++j) cb[j] = nb[j]; \
  } \
  ph[PH][mn] = (a0 + a1) + (a2 + a3); }

// group 0 from registers (w0c), groups 1..3 streamed (r7 loop text)
#define STREAM3(PH) { \
  float a0 = 0, a1 = 0, a2 = 0, a3 = 0; \
  uint4 cb[8], nb[8]; \
  _Pragma("unroll") \
  for (int j = 0; j < 8; ++j) cb[j] = Wp[(size_t)(8 + j) * 512]; \
  _Pragma("unroll") \
  for (int j = 0; j < 8; ++j) { \
    uint4 wv = w0c[j]; uint4 xv = hp4[hbase + j]; \
    a0 = fdot2(wv.x, xv.x, a0); a1 = fdot2(wv.y, xv.y, a1); \
    a2 = fdot2(wv.z, xv.z, a2); a3 = fdot2(wv.w, xv.w, a3); \
  } \
  for (int blk = 1; blk < 4; ++blk) { \
    if (blk + 1 < 4) { \
      _Pragma("unroll") \
      for (int j = 0; j < 8; ++j) nb[j] = Wp[(size_t)((blk + 1) * 8 + j) * 512]; \
    } \
    _Pragma("unroll") \
    for (int j = 0; j < 8; ++j) { \
      uint4 wv = cb[j]; uint4 xv = hp4[hbase + blk * 8 + j]; \
      a0 = fdot2(wv.x, xv.x, a0); a1 = fdot2(wv.y, xv.y, a1); \
      a2 = fdot2(wv.z, xv.z, a2); a3 = fdot2(wv.w, xv.w, a3); \
    } \
    _Pragma("unroll") \
    for (int j = 0; j < 8; ++j) cb[j] = nb[j]; \
  } \
  ph[PH][mn] = (a0 + a1) + (a2 + a3); }

__global__ __launch_bounds__(1024) void k_recur(
    const float* __restrict__ We1,
    const float* __restrict__ be1,
    const float* __restrict__ We2,
    const float* __restrict__ be2,
    const uint4* __restrict__ W2,
    const uint4* __restrict__ encW2,
    const unsigned short* __restrict__ Remb,
    const float* __restrict__ E1g,
    unsigned short* __restrict__ X,
    float* __restrict__ wout,
    const float* __restrict__ Wo,
    unsigned short* __restrict__ WoT,
    const float* __restrict__ enc,
    unsigned short* __restrict__ encTh)
{
  __shared__ __align__(16) uint4 el[16][512];
  __shared__ uint32_t E1p[HE][SLEN / 2];
  __shared__ uint32_t w1p[HE][257];
  __shared__ uint32_t hpair[DECD / 2];
  __shared__ uint32_t wpairS[SLEN / 2];
  __shared__ float ph[2][DECD];
  __shared__ float be1s[HE], w2s[HE];
  __shared__ float be2s;

  int bid = blockIdx.x, tid = threadIdx.x;

  if (bid >= 64) {
    float (*tile)[65] = (float(*)[65])el;
    if (bid < 704) {
      for (int q = 0; q < 4; ++q) {
        int t4 = (bid - 64) * 4 + q;
        int n0 = (t4 % 128) * 64, k0 = (t4 / 128) * 64;
        for (int i = tid; i < 4096; i += 1024) {
          int kk = i >> 6, nn = i & 63;
          int n = n0 + nn;
          tile[kk][nn] = (n < VOC) ? Wo[(size_t)(k0 + kk) * VOC + n] : 0.f;
        }
        __syncthreads();
        for (int i = tid; i < 4096; i += 1024) {
          int nn = i >> 6, kk = i & 63;
          WoT[(size_t)(n0 + nn) * KX + k0 + kk] = f2bf(tile[kk][nn]);
        }
        __syncthreads();
      }
    } else {
      for (int q = 0; q < 4; ++q) {
        int t4 = (bid - 704) * 4 + q;
        int eb_ = t4 >> 4;
        int e0 = ((t4 >> 1) & 7) * 64;
        int s0 = (t4 & 1) * 64;
        const float* ebp = enc + (size_t)eb_ * SLEN * ENCD;
        for (int i = tid; i < 4096; i += 1024) {
          int ss = i >> 6, ee = i & 63;
          tile[ss][ee] = ebp[(size_t)(s0 + ss) * ENCD + e0 + ee];
        }
        __syncthreads();
        unsigned short* ob = encTh + (size_t)eb_ * ENCD * SLEN;
        for (int i = tid; i < 4096; i += 1024) {
          int ee = i >> 6, ss = i & 63;
          ob[(size_t)(e0 + ee) * SLEN + s0 + ss] = f16bits(tile[ss][ee]);
        }
        __syncthreads();
      }
    }
    return;
  }

  int b = bid;

  for (int i = tid; i < 16 * 512; i += 1024) ((uint4*)el)[i] = encW2[(size_t)b * 8192 + i];
  for (int i = tid; i < HE * (SLEN / 2); i += 1024) {
    int h = i >> 6, p = i & 63;
    const float* ebase = E1g + ((size_t)b * HE + h) * SLEN;
    ((uint32_t*)E1p)[i] = pkh2(ebase[2 * p], ebase[2 * p + 1]);
  }
  for (int i = tid; i < HE * 256; i += 1024) {
    int h = i >> 8, p = i & 255;
    w1p[h][p] = pkh2(We1[(size_t)(ENCD + 2 * p) * HE + h],
                     We1[(size_t)(ENCD + 2 * p + 1) * HE + h]);
  }
  for (int i = tid; i < DECD / 2; i += 1024) hpair[i] = 0;
  for (int i = tid; i < DECD; i += 1024) { ph[0][i] = 0.f; ph[1][i] = 0.f; }
  if (tid < HE) { be1s[tid] = be1[tid]; w2s[tid] = We2[tid]; }
  if (tid == 0) be2s = be2[0];
  __syncthreads();

  const int lane = tid & 63;
  const int wv_ = tid >> 6;
  int mn, mh0;
  if (tid < 448)      { mn = tid;        mh0 = 0; }
  else if (tid < 896) { mn = tid - 448;  mh0 = 1; }
  else if (tid < 960) { mn = 448 + lane; mh0 = 0; }
  else                { mn = 448 + lane; mh0 = 1; }
  const uint4* Wp = W2 + (size_t)(mh0 * 32) * 512 + mn;
  const uint4* hp4 = (const uint4*)hpair;
  const int hbase = mh0 * 32;

  // persistent register cache of W2 group 0 (waves 0..14 only; never
  // live across the attention branch)
  uint4 w0c[8];
  if (wv_ < 15) {
    #pragma unroll
    for (int j = 0; j < 8; ++j) w0c[j] = Wp[(size_t)j * 512];
  }

  int ah = lane % 20, aseg = lane / 20;
  int q0 = aseg * 86;
  int q1 = (aseg == 2) ? 256 : q0 + 86;
  if (aseg >= 3) { q0 = 0; q1 = 0; }

  for (int t = 0; t < TLEN; ++t) {
    const int rowr = t * BATCH + b;
    float rpre = 0.f;

    if (wv_ < 15) {
      if (tid < 512) {
        union { unsigned short u; _Float16 f; } c;
        c.u = Remb[(size_t)rowr * 512 + tid];
        rpre = (float)c.f;
      }
      STREAM3(mh0)
    } else {
      __builtin_amdgcn_s_setprio(1);
      float p0 = 0, p1 = 0;
      for (int q = q0; q < q1; q += 2) {
        p0 = fdot2(w1p[ah][q], hpair[q], p0);
        p1 = fdot2(w1p[ah][q + 1], hpair[q + 1], p1);
      }
      float p = p0 + p1;
      float pa = __shfl(p, lane + 20);
      float pb = __shfl(p, lane + 40);
      float edv = p + pa + pb + ((lane < HE) ? be1s[lane] : 0.f);
      float e0a = 0.f, e1a = 0.f;
      #pragma unroll
      for (int h = 0; h < HE; ++h) {
        union { uint32_t u; h2 hh; } e; e.u = E1p[h][lane];
        float ed = __shfl(edv, h);
        e0a += eluf((float)e.hh[0] + ed) * w2s[h];
        e1a += eluf((float)e.hh[1] + ed) * w2s[h];
      }
      float s0 = expf(eluf(e0a + be2s));
      float s1 = expf(eluf(e1a + be2s));
      float tot = s0 + s1;
      #pragma unroll
      for (int o = 1; o < 64; o <<= 1) tot += __shfl_xor(tot, o);
      float inv = 1.f / tot;
      float w0 = s0 * inv, w1 = s1 * inv;
      wpairS[lane] = pkh2(w0, w1);
      float2 wv2 = { w0, w1 };
      *(float2*)(wout + ((size_t)b * TLEN + t) * SLEN + 2 * lane) = wv2;
      __builtin_amdgcn_s_setprio(0);
      STREAM4(1)
    }
    __syncthreads();

    if (tid < 512) {
      int n = tid;
      float c0 = 0, c1 = 0, c2 = 0, c3 = 0;
      #pragma unroll
      for (int g = 0; g < 16; ++g) {
        uint4 ev = el[g][n];
        uint4 wv = ((const uint4*)wpairS)[g];
        c0 = fdot2(ev.x, wv.x, c0); c1 = fdot2(ev.y, wv.y, c1);
        c2 = fdot2(ev.z, wv.z, c2); c3 = fdot2(ev.w, wv.w, c3);
      }
      float v = rpre + ph[0][n] + ph[1][n] + (c0 + c1) + (c2 + c3);
      float aa = eluf(v);
      X[(size_t)rowr * KX + 256 + n] = f2bf(aa);
      float bb = __shfl_down(aa, 1);
      if (!(n & 1)) hpair[n >> 1] = pkh2(aa, bb);
    }
    __syncthreads();
  }
}

// ---------- k_gemm: 256x256 8-wave, double-buffered LDS, counted vmcnt ----------
#define GSTAGE(KT, C) { _Pragma("unroll") \
  for (int j5 = 0; j5 < 4; ++j5) { \
    int c4 = tid + j5 * 512; \
    int r5 = c4 >> 3, c16 = c4 & 7; \
    int sk = c16 ^ (r5 & 7); \
    gload16(Abase + (size_t)r5 * KX + (KT) * 64 + sk * 8, (char*)Ah[C] + c4 * 16); \
  } \
  _Pragma("unroll") \
  for (int j5 = 0; j5 < 4; ++j5) { \
    int c4 = tid + j5 * 512; \
    int r5 = c4 >> 3, c16 = c4 & 7; \
    int sk = c16 ^ (r5 & 7); \
    gload16(Bbase + (size_t)r5 * KX + (KT) * 64 + sk * 8, (char*)Bh[C] + c4 * 16); \
  } }

__global__ __launch_bounds__(512) void k_gemm(
    const unsigned short* __restrict__ Xb,
    const unsigned short* __restrict__ WoT,
    const float* __restrict__ bout,
    float* __restrict__ out)
{
  __shared__ __align__(16) unsigned short Ah[2][256 * 64];
  __shared__ __align__(16) unsigned short Bh[2][256 * 64];
  int bid = blockIdx.x;
  int swz = (bid & 7) * 128 + (bid >> 3);
  int by = swz >> 5, bx = swz & 31;
  int tid = threadIdx.x;
  int lane = tid & 63;
  int wid = tid >> 6;
  int wrow = wid >> 2, wcol = wid & 3;

  const unsigned short* Abase = Xb + (size_t)by * 256 * KX;
  const unsigned short* Bbase = WoT + (size_t)bx * 256 * KX;

  f32x4 acc[8][4];
  #pragma unroll
  for (int i = 0; i < 8; ++i)
    #pragma unroll
    for (int j = 0; j < 4; ++j) acc[i][j] = (f32x4)0.f;

  GSTAGE(0, 0)
  GSTAGE(1, 1)
  asm volatile("s_waitcnt vmcnt(8)" ::: "memory");
  __builtin_amdgcn_s_barrier();
  __builtin_amdgcn_sched_barrier(0);

  for (int kt = 0; kt < 20; ++kt) {
    int c = kt & 1;
    const char* Ab = (const char*)Ah[c];
    const char* Bb = (const char*)Bh[c];
    short8 af[4][2], bf[4][2];
    #pragma unroll
    for (int i = 0; i < 4; ++i)
      #pragma unroll
      for (int ks = 0; ks < 2; ++ks) {
        int rw = wrow * 128 + i * 16 + (lane & 15);
        int kc = ks * 4 + (lane >> 4);
        af[i][ks] = *(const short8*)(Ab + rw * 128 + ((kc ^ (rw & 7)) * 16));
      }
    #pragma unroll
    for (int j = 0; j < 4; ++j)
      #pragma unroll
      for (int ks = 0; ks < 2; ++ks) {
        int rb = wcol * 64 + j * 16 + (lane & 15);
        int kc = ks * 4 + (lane >> 4);
        bf[j][ks] = *(const short8*)(Bb + rb * 128 + ((kc ^ (rb & 7)) * 16));
      }
    __builtin_amdgcn_s_setprio(1);
    #pragma unroll
    for (int i = 0; i < 4; ++i)
      #pragma unroll
      for (int j = 0; j < 4; ++j)
        #pragma unroll
        for (int ks = 0; ks < 2; ++ks)
          acc[i][j] = __builtin_amdgcn_mfma_f32_16x16x32_bf16(af[i][ks], bf[j][ks], acc[i][j], 0, 0, 0);
    __builtin_amdgcn_s_setprio(0);
    #pragma unroll
    for (int i = 0; i < 4; ++i)
      #pragma unroll
      for (int ks = 0; ks < 2; ++ks) {
        int rw = wrow * 128 + 64 + i * 16 + (lane & 15);
        int kc = ks * 4 + (lane >> 4);
        af[i][ks] = *(const short8*)(Ab + rw * 128 + ((kc ^ (rw & 7)) * 16));
      }
    __builtin_amdgcn_s_setprio(1);
    #pragma unroll
    for (int i = 0; i < 4; ++i)
      #pragma unroll
      for (int j = 0; j < 2; ++j)
        #pragma unroll
        for (int ks = 0; ks < 2; ++ks)
          acc[4 + i][j] = __builtin_amdgcn_mfma_f32_16x16x32_bf16(af[i][ks], bf[j][ks], acc[4 + i][j], 0, 0, 0);
    __builtin_amdgcn_s_setprio(0);
    __builtin_amdgcn_s_barrier();
    __builtin_amdgcn_sched_barrier(0);
    if (kt < 18) GSTAGE(kt + 2, c)
    __builtin_amdgcn_s_setprio(1);
    #pragma unroll
    for (int i = 0; i < 4; ++i)
      #pragma unroll
      for (int j = 0; j < 2; ++j)
        #pragma unroll
        for (int ks = 0; ks < 2; ++ks)
          acc[4 + i][2 + j] = __builtin_amdgcn_mfma_f32_16x16x32_bf16(af[i][ks], bf[2 + j][ks], acc[4 + i][2 + j], 0, 0, 0);
    __builtin_amdgcn_s_setprio(0);
    if (kt < 18) { asm volatile("s_waitcnt vmcnt(8)" ::: "memory"); }
    else         { asm volatile("s_waitcnt vmcnt(0)" ::: "memory"); }
    __builtin_amdgcn_s_barrier();
    __builtin_amdgcn_sched_barrier(0);
  }

  int rl = lane >> 4, cl = lane & 15;
  #pragma unroll
  for (int j = 0; j < 4; ++j) {
    int gn = bx * 256 + wcol * 64 + j * 16 + cl;
    if (gn >= VOC) continue;
    float bv = bout[gn];
    #pragma unroll
    for (int i = 0; i < 8; ++i) {
      #pragma unroll
      for (int q = 0; q < 4; ++q) {
        int gm = by * 256 + wrow * 128 + i * 16 + rl * 4 + q;
        int tt = gm >> 6, bb = gm & 63;
        float v = acc[i][j][q] + bv;
        v = v > 0.f ? v : (expf(v) - 1.f);
        out[((size_t)bb * TLEN + tt) * VOC + gn] = v;
      }
    }
  }
}

// ---------- launch ----------
extern "C" void kernel_launch(void* const* d_in, const int* in_sizes, int n_in,
                              void* d_out, int out_size, void* d_ws, size_t ws_size,
                              hipStream_t stream) {
  const float* enc  = (const float*)d_in[0];
  const int*   ro   = (const int*)d_in[1];
  const float* We1  = (const float*)d_in[2];
  const float* be1  = (const float*)d_in[3];
  const float* We2  = (const float*)d_in[4];
  const float* be2  = (const float*)d_in[5];
  const float* emb  = (const float*)d_in[6];
  const float* Wr   = (const float*)d_in[7];
  const float* brnn = (const float*)d_in[8];
  const float* Wo   = (const float*)d_in[9];
  const float* bo   = (const float*)d_in[10];

  char* ws = (char*)d_ws;
  unsigned short* X     = (unsigned short*)(ws);                 // 20,971,520
  unsigned short* WoT   = (unsigned short*)(ws + 20971520);      // 20,971,520 (8192 rows)
  unsigned short* W2    = (unsigned short*)(ws + 41943040);      //    524,288
  unsigned short* WembT = (unsigned short*)(ws + 42467328);      //    262,144
  unsigned short* WctxT = (unsigned short*)(ws + 42729472);      //    524,288
  unsigned short* ench  = (unsigned short*)(ws + 43253760);      //  8,388,608 (reused: encTh)
  float*          E1    = (float*)(ws + 51642368);               //    655,360
  unsigned short* Remb  = (unsigned short*)(ws + 52297728);      //  8,388,608 (reused: wh)
  unsigned short* encW2 = (unsigned short*)(ws + 60686336);      //  8,388,608
  unsigned short* encTh = ench;
  unsigned short* wh    = Remb;

  float* outs = (float*)d_out;
  float* wout = (float*)d_out + (size_t)BATCH * TLEN * VOC;

  k_pre1 <<<dim3(14336),    256, 0, stream>>>(ro, emb, X, enc, ench, We1, E1);
  k_pre2 <<<dim3(1120),     256, 0, stream>>>(Wr, WembT, WctxT, W2);
  k_gs01 <<<dim3(4, 64, 2), 256, 0, stream>>>(X, WembT, ench, WctxT, brnn, Remb, encW2);
  k_recur<<<dim3(960),     1024, 0, stream>>>(We1, be1, We2, be2,
                                              (const uint4*)W2, (const uint4*)encW2,
                                              Remb, E1, X, wout,
                                              Wo, WoT, enc, encTh);
  k_wh   <<<dim3(1024),     256, 0, stream>>>(wout, wh);
  k_gs2  <<<dim3(4, 64),    256, 0, stream>>>(wh, encTh, brnn, X);
  k_gemm <<<dim3(1024),     512, 0, stream>>>(X, WoT, bo, outs);
  (void)in_sizes; (void)n_in; (void)out_size; (void)ws_size;
}

// Round 16
// 1178.400 us; speedup vs baseline: 1.1611x; 1.1611x over previous
//
#include <hip/hip_runtime.h>
#include <hip/hip_bf16.h>
#include <stdint.h>

#define BATCH 64
#define SLEN 128
#define TLEN 128
#define ENCD 512
#define DECD 512
#define EMBD 256
#define VOC  8000
#define HE   20
#define KX   1280      // EMB + DEC + ENC
#define NP2  8192      // VOC padded to 32*256

typedef __attribute__((ext_vector_type(8))) short short8;
typedef __attribute__((ext_vector_type(8))) _Float16 half8v;
typedef __attribute__((ext_vector_type(4))) float f32x4;
typedef _Float16 h2 __attribute__((ext_vector_type(2)));

// ---------- helpers ----------
__device__ inline unsigned short f2bf(float f) {
  union { float f; uint32_t u; } v; v.f = f;
  uint32_t r = v.u + 0x7fff + ((v.u >> 16) & 1);
  return (unsigned short)(r >> 16);
}
__device__ inline unsigned short f16bits(float f) {
  union { _Float16 h; unsigned short u; } c; c.h = (_Float16)f; return c.u;
}
__device__ inline uint32_t pkh2(float a, float b) {
  union { h2 h; uint32_t u; } v;
  v.h = h2{(_Float16)a, (_Float16)b};
  return v.u;
}
__device__ inline float fdot2(uint32_t a, uint32_t b, float c) {
#if __has_builtin(__builtin_amdgcn_fdot2)
  union { uint32_t u; h2 h; } x, y; x.u = a; y.u = b;
  return __builtin_amdgcn_fdot2(x.h, y.h, c, false);
#else
  union { uint32_t u; h2 h; } x, y; x.u = a; y.u = b;
  return c + (float)x.h[0] * (float)y.h[0] + (float)x.h[1] * (float)y.h[1];
#endif
}
__device__ inline float eluf(float x) { return x > 0.f ? x : (expf(x) - 1.f); }

typedef const __attribute__((address_space(1))) unsigned int* gptr_t;
typedef __attribute__((address_space(3))) unsigned int* lptr_t;
__device__ inline void gload16(const void* g, void* l) {
  __builtin_amdgcn_global_load_lds((gptr_t)g, (lptr_t)l, 16, 0, 0);
}

// ---------- k_pre1: merged k_lc / k_ench / k_e1 ----------
__global__ __launch_bounds__(256) void k_pre1(const int* __restrict__ ro,
                                              const float* __restrict__ emb,
                                              unsigned short* __restrict__ X,
                                              const float* __restrict__ enc,
                                              unsigned short* __restrict__ ench,
                                              const float* __restrict__ We1,
                                              float* __restrict__ E1) {
  __shared__ float rowbuf[4][ENCD];
  __shared__ float part[4][HE][2];
  int bid = blockIdx.x, tid = threadIdx.x;
  if (bid < 8192) {
    int r = bid;
    int t = r >> 6, b = r & 63;
    int lc = (t == 0) ? 0 : ro[b * TLEN + t - 1];
    lc = ((lc % VOC) + VOC) % VOC;
    X[(size_t)r * KX + tid] = f2bf(emb[(size_t)lc * EMBD + tid]);
  } else if (bid < 12288) {
    int i = ((bid - 8192) * 256 + tid) * 4;
    float4 v = *(const float4*)(enc + i);
    ushort4 o = { f16bits(v.x), f16bits(v.y), f16bits(v.z), f16bits(v.w) };
    *(ushort4*)(ench + i) = o;
  } else {
    int r0 = (bid - 12288) * 4;
    for (int i = tid; i < 4 * ENCD; i += 256) {
      int rl = i >> 9, e = i & 511;
      rowbuf[rl][e] = enc[(size_t)(r0 + rl) * ENCD + e];
    }
    __syncthreads();
    if (tid < 160) {
      int kg = tid / 80, rem = tid % 80, rl = rem / 20, h = rem % 20;
      float acc = 0.f;
      for (int k = kg * 256; k < kg * 256 + 256; ++k)
        acc += rowbuf[rl][k] * We1[k * HE + h];
      part[rl][h][kg] = acc;
    }
    __syncthreads();
    if (tid < 80) {
      int rl = tid / 20, h = tid % 20;
      int r = r0 + rl, bb = r >> 7, ss = r & 127;
      E1[((size_t)bb * HE + h) * SLEN + ss] = part[rl][h][0] + part[rl][h][1];
    }
  }
}

// ---------- k_pre2: merged k_tr_w(WembT) / k_tr_w(WctxT) / k_prep_wr ----------
__global__ __launch_bounds__(256) void k_pre2(const float* __restrict__ Wr,
                                              unsigned short* __restrict__ WembT,
                                              unsigned short* __restrict__ WctxT,
                                              unsigned short* __restrict__ W2) {
  __shared__ float tile[64][65];
  int bid = blockIdx.x, tid = threadIdx.x;
  if (bid < 96) {
    int k0, KN, fmt, bx, by;
    unsigned short* dst;
    if (bid < 32) { k0 = 0;   KN = 256; fmt = 1; bx = bid & 7; by = bid >> 3; dst = WembT; }
    else          { int id2 = bid - 32; k0 = 768; KN = 512; fmt = 0; bx = id2 & 7; by = id2 >> 3; dst = WctxT; }
    int n0 = bx * 64, kt = by * 64;
    for (int i = tid; i < 4096; i += 256) {
      int kk = i >> 6, nn = i & 63;
      tile[kk][nn] = Wr[(size_t)(k0 + kt + kk) * 512 + n0 + nn];
    }
    __syncthreads();
    for (int i = tid; i < 4096; i += 256) {
      int nn = i >> 6, kk = i & 63;
      float v = tile[kk][nn];
      dst[(size_t)(n0 + nn) * KN + kt + kk] = fmt ? f2bf(v) : f16bits(v);
    }
  } else {
    int i = (bid - 96) * 256 + tid;
    int n = i & 511;
    int j = (i >> 9) & 7;
    int kc = (i >> 12) & 31;
    int h = (i >> 17) & 1;
    int k = h * 256 + kc * 8 + j;
    W2[(((size_t)(h * 32 + kc) * 512) + n) * 8 + j] = f16bits(Wr[(size_t)(256 + k) * 512 + n]);
  }
}

// ---------- k_wh: wout f32 [8192][128] -> f16 ----------
__global__ __launch_bounds__(256) void k_wh(const float* __restrict__ wout,
                                            unsigned short* __restrict__ wh) {
  int i = (blockIdx.x * 256 + threadIdx.x) * 4;
  float4 v = *(const float4*)(wout + i);
  ushort4 o = { f16bits(v.x), f16bits(v.y), f16bits(v.z), f16bits(v.w) };
  *(ushort4*)(wh + i) = o;
}

// ---------- gs_body<MODE>: 128x128xK MFMA GEMM body ----------
#define BM 128
#define BN 128
#define BK 64

template<int MODE>
__device__ __forceinline__ void gs_body(
    unsigned short* Asd, unsigned short* Bsd,
    const unsigned short* __restrict__ A,
    const unsigned short* __restrict__ B,
    const float* __restrict__ bias,
    unsigned short* __restrict__ Cout,
    int bx, int by, int tid)
{
  constexpr int As = (MODE == 0) ? KX : (MODE == 1 ? 512 : 128);
  constexpr int Bs = (MODE == 0) ? 256 : (MODE == 1 ? 512 : 128);
  constexpr int KT = (MODE == 0) ? 4 : (MODE == 1 ? 8 : 2);
  int wid = tid >> 6, lane = tid & 63;
  int wr = wid >> 1, wc = wid & 1;

  f32x4 acc[4][4];
  for (int i = 0; i < 4; ++i)
    for (int j = 0; j < 4; ++j) acc[i][j] = (f32x4)0.f;

  const unsigned short* Abase = A + (size_t)by * BM * As;
  const unsigned short* Bbase = B + (size_t)bx * BN * Bs + (MODE == 2 ? (size_t)by * 512 * 128 : 0);

  for (int kt = 0; kt < KT; ++kt) {
    for (int j = 0; j < 4; ++j) {
      int c = tid + j * 256;
      int r = c >> 3, c16 = c & 7;
      int sk = c16 ^ (r & 7);
      gload16(Abase + (size_t)r * As + kt * BK + sk * 8, (char*)Asd + c * 16);
      gload16(Bbase + (size_t)r * Bs + kt * BK + sk * 8, (char*)Bsd + c * 16);
    }
    __syncthreads();
    for (int ks = 0; ks < 2; ++ks) {
      short8 af[4], bf[4];
      int kc = ks * 4 + (lane >> 4);
      for (int i = 0; i < 4; ++i) {
        int r = wr * 64 + i * 16 + (lane & 15);
        af[i] = *(const short8*)((const char*)Asd + r * 128 + ((kc ^ (r & 7)) * 16));
      }
      for (int j = 0; j < 4; ++j) {
        int r = wc * 64 + j * 16 + (lane & 15);
        bf[j] = *(const short8*)((const char*)Bsd + r * 128 + ((kc ^ (r & 7)) * 16));
      }
      for (int i = 0; i < 4; ++i)
        for (int j = 0; j < 4; ++j) {
          if constexpr (MODE == 0)
            acc[i][j] = __builtin_amdgcn_mfma_f32_16x16x32_bf16(af[i], bf[j], acc[i][j], 0, 0, 0);
          else
            acc[i][j] = __builtin_amdgcn_mfma_f32_16x16x32_f16(
                __builtin_bit_cast(half8v, af[i]), __builtin_bit_cast(half8v, bf[j]), acc[i][j], 0, 0, 0);
        }
    }
    __syncthreads();
  }

  int rl = lane >> 4, cl = lane & 15;
  for (int j = 0; j < 4; ++j) {
    int gn = bx * BN + wc * 64 + j * 16 + cl;
    for (int i = 0; i < 4; ++i) {
      for (int q = 0; q < 4; ++q) {
        int gm = by * BM + wr * 64 + i * 16 + rl * 4 + q;
        float v = acc[i][j][q];
        if constexpr (MODE == 0) {
          Cout[(size_t)gm * 512 + gn] = f16bits(v + bias[gn]);
        } else if constexpr (MODE == 1) {
          int bb = gm >> 7, s = gm & 127;
          Cout[(((size_t)(bb * 16 + (s >> 3)) * 512) + gn) * 8 + (s & 7)] = f16bits(v);
        } else {
          int tt = gm & 127, bb = gm >> 7;
          Cout[((size_t)tt * 64 + bb) * KX + 768 + gn] = f2bf(v);
        }
      }
    }
  }
}

// ---------- k_gs01: MODE0 (z=0) and MODE1 (z=1) in one launch ----------
__global__ __launch_bounds__(256) void k_gs01(
    const unsigned short* __restrict__ X,
    const unsigned short* __restrict__ WembT,
    const unsigned short* __restrict__ ench,
    const unsigned short* __restrict__ WctxT,
    const float* __restrict__ brnn,
    unsigned short* __restrict__ Remb,
    unsigned short* __restrict__ encW2)
{
  __shared__ __align__(16) unsigned short Asd[BM * BK];
  __shared__ __align__(16) unsigned short Bsd[BN * BK];
  if (blockIdx.z == 0)
    gs_body<0>(Asd, Bsd, X, WembT, brnn, Remb, blockIdx.x, blockIdx.y, threadIdx.x);
  else
    gs_body<1>(Asd, Bsd, ench, WctxT, brnn, encW2, blockIdx.x, blockIdx.y, threadIdx.x);
}

// ---------- k_gs2: MODE2 (ctx fill) ----------
__global__ __launch_bounds__(256) void k_gs2(
    const unsigned short* __restrict__ wh,
    const unsigned short* __restrict__ encTh,
    const float* __restrict__ brnn,
    unsigned short* __restrict__ X)
{
  __shared__ __align__(16) unsigned short Asd[BM * BK];
  __shared__ __align__(16) unsigned short Bsd[BN * BK];
  gs_body<2>(Asd, Bsd, wh, encTh, brnn, X, blockIdx.x, blockIdx.y, threadIdx.x);
}

// ---------- k_recur: r10/r14 recurrence (blocks 0..63) + independent transposes ----------
// blocks 64..703 : W_out -> WoT [8192][1280] bf16 (zero-pad, 4 tiles each)
// blocks 704..959: enc -> encTh [b][e][s] f16 (4 tiles each)
#define STREAM4(PH) { \
  float a0 = 0, a1 = 0, a2 = 0, a3 = 0; \
  uint4 cb[8], nb[8]; \
  _Pragma("unroll") \
  for (int j = 0; j < 8; ++j) cb[j] = Wp[(size_t)j * 512]; \
  for (int blk = 0; blk < 4; ++blk) { \
    if (blk + 1 < 4) { \
      _Pragma("unroll") \
      for (int j = 0; j < 8; ++j) nb[j] = Wp[(size_t)((blk + 1) * 8 + j) * 512]; \
    } \
    _Pragma("unroll") \
    for (int j = 0; j < 8; ++j) { \
      uint4 wv = cb[j]; uint4 xv = hp4[hbase + blk * 8 + j]; \
      a0 = fdot2(wv.x, xv.x, a0); a1 = fdot2(wv.y, xv.y, a1); \
      a2 = fdot2(wv.z, xv.z, a2); a3 = fdot2(wv.w, xv.w, a3); \
    } \
    _Pragma("unroll") \
    for (int j = 0; j < 8; ++j) cb[j] = nb[j]; \
  } \
  ph[PH][mn] = (a0 + a1) + (a2 + a3); }

__global__ __launch_bounds__(1024) void k_recur(
    const float* __restrict__ We1,
    const float* __restrict__ be1,
    const float* __restrict__ We2,
    const float* __restrict__ be2,
    const uint4* __restrict__ W2,
    const uint4* __restrict__ encW2,
    const unsigned short* __restrict__ Remb,
    const float* __restrict__ E1g,
    unsigned short* __restrict__ X,
    float* __restrict__ wout,
    const float* __restrict__ Wo,
    unsigned short* __restrict__ WoT,
    const float* __restrict__ enc,
    unsigned short* __restrict__ encTh)
{
  __shared__ __align__(16) uint4 el[16][512];
  __shared__ uint32_t E1p[HE][SLEN / 2];
  __shared__ uint32_t w1p[HE][257];
  __shared__ uint32_t hpair[DECD / 2];
  __shared__ uint32_t wpairS[SLEN / 2];
  __shared__ float ph[2][DECD];
  __shared__ float be1s[HE], w2s[HE];
  __shared__ float be2s;

  int bid = blockIdx.x, tid = threadIdx.x;

  if (bid >= 64) {
    float (*tile)[65] = (float(*)[65])el;
    if (bid < 704) {
      for (int q = 0; q < 4; ++q) {
        int t4 = (bid - 64) * 4 + q;
        int n0 = (t4 % 128) * 64, k0 = (t4 / 128) * 64;
        for (int i = tid; i < 4096; i += 1024) {
          int kk = i >> 6, nn = i & 63;
          int n = n0 + nn;
          tile[kk][nn] = (n < VOC) ? Wo[(size_t)(k0 + kk) * VOC + n] : 0.f;
        }
        __syncthreads();
        for (int i = tid; i < 4096; i += 1024) {
          int nn = i >> 6, kk = i & 63;
          WoT[(size_t)(n0 + nn) * KX + k0 + kk] = f2bf(tile[kk][nn]);
        }
        __syncthreads();
      }
    } else {
      for (int q = 0; q < 4; ++q) {
        int t4 = (bid - 704) * 4 + q;
        int eb_ = t4 >> 4;
        int e0 = ((t4 >> 1) & 7) * 64;
        int s0 = (t4 & 1) * 64;
        const float* ebp = enc + (size_t)eb_ * SLEN * ENCD;
        for (int i = tid; i < 4096; i += 1024) {
          int ss = i >> 6, ee = i & 63;
          tile[ss][ee] = ebp[(size_t)(s0 + ss) * ENCD + e0 + ee];
        }
        __syncthreads();
        unsigned short* ob = encTh + (size_t)eb_ * ENCD * SLEN;
        for (int i = tid; i < 4096; i += 1024) {
          int ee = i >> 6, ss = i & 63;
          ob[(size_t)(e0 + ee) * SLEN + s0 + ss] = f16bits(tile[ss][ee]);
        }
        __syncthreads();
      }
    }
    return;
  }

  int b = bid;

  for (int i = tid; i < 16 * 512; i += 1024) ((uint4*)el)[i] = encW2[(size_t)b * 8192 + i];
  for (int i = tid; i < HE * (SLEN / 2); i += 1024) {
    int h = i >> 6, p = i & 63;
    const float* ebase = E1g + ((size_t)b * HE + h) * SLEN;
    ((uint32_t*)E1p)[i] = pkh2(ebase[2 * p], ebase[2 * p + 1]);
  }
  for (int i = tid; i < HE * 256; i += 1024) {
    int h = i >> 8, p = i & 255;
    w1p[h][p] = pkh2(We1[(size_t)(ENCD + 2 * p) * HE + h],
                     We1[(size_t)(ENCD + 2 * p + 1) * HE + h]);
  }
  for (int i = tid; i < DECD / 2; i += 1024) hpair[i] = 0;
  for (int i = tid; i < DECD; i += 1024) { ph[0][i] = 0.f; ph[1][i] = 0.f; }
  if (tid < HE) { be1s[tid] = be1[tid]; w2s[tid] = We2[tid]; }
  if (tid == 0) be2s = be2[0];
  __syncthreads();

  const int lane = tid & 63;
  const int wv_ = tid >> 6;
  int mn, mh0;
  if (tid < 448)      { mn = tid;        mh0 = 0; }
  else if (tid < 896) { mn = tid - 448;  mh0 = 1; }
  else if (tid < 960) { mn = 448 + lane; mh0 = 0; }
  else                { mn = 448 + lane; mh0 = 1; }
  const uint4* Wp = W2 + (size_t)(mh0 * 32) * 512 + mn;
  const uint4* hp4 = (const uint4*)hpair;
  const int hbase = mh0 * 32;

  int ah = lane % 20, aseg = lane / 20;
  int q0 = aseg * 86;
  int q1 = (aseg == 2) ? 256 : q0 + 86;
  if (aseg >= 3) { q0 = 0; q1 = 0; }

  for (int t = 0; t < TLEN; ++t) {
    const int rowr = t * BATCH + b;
    float rpre = 0.f;

    if (wv_ < 15) {
      if (tid < 512) {
        union { unsigned short u; _Float16 f; } c;
        c.u = Remb[(size_t)rowr * 512 + tid];
        rpre = (float)c.f;
      }
      STREAM4(mh0)
    } else {
      __builtin_amdgcn_s_setprio(1);
      float p0 = 0, p1 = 0;
      for (int q = q0; q < q1; q += 2) {
        p0 = fdot2(w1p[ah][q], hpair[q], p0);
        p1 = fdot2(w1p[ah][q + 1], hpair[q + 1], p1);
      }
      float p = p0 + p1;
      float pa = __shfl(p, lane + 20);
      float pb = __shfl(p, lane + 40);
      float edv = p + pa + pb + ((lane < HE) ? be1s[lane] : 0.f);
      float e0a = 0.f, e1a = 0.f;
      #pragma unroll
      for (int h = 0; h < HE; ++h) {
        union { uint32_t u; h2 hh; } e; e.u = E1p[h][lane];
        float ed = __shfl(edv, h);
        e0a += eluf((float)e.hh[0] + ed) * w2s[h];
        e1a += eluf((float)e.hh[1] + ed) * w2s[h];
      }
      float s0 = expf(eluf(e0a + be2s));
      float s1 = expf(eluf(e1a + be2s));
      float tot = s0 + s1;
      #pragma unroll
      for (int o = 1; o < 64; o <<= 1) tot += __shfl_xor(tot, o);
      float inv = 1.f / tot;
      float w0 = s0 * inv, w1 = s1 * inv;
      wpairS[lane] = pkh2(w0, w1);
      float2 wv2 = { w0, w1 };
      *(float2*)(wout + ((size_t)b * TLEN + t) * SLEN + 2 * lane) = wv2;
      __builtin_amdgcn_s_setprio(0);
      STREAM4(1)
    }
    __syncthreads();

    if (tid < 512) {
      int n = tid;
      float c0 = 0, c1 = 0, c2 = 0, c3 = 0;
      #pragma unroll
      for (int g = 0; g < 16; ++g) {
        uint4 ev = el[g][n];
        uint4 wv = ((const uint4*)wpairS)[g];
        c0 = fdot2(ev.x, wv.x, c0); c1 = fdot2(ev.y, wv.y, c1);
        c2 = fdot2(ev.z, wv.z, c2); c3 = fdot2(ev.w, wv.w, c3);
      }
      float v = rpre + ph[0][n] + ph[1][n] + (c0 + c1) + (c2 + c3);
      float aa = eluf(v);
      X[(size_t)rowr * KX + 256 + n] = f2bf(aa);
      float bb = __shfl_down(aa, 1);
      if (!(n & 1)) hpair[n >> 1] = pkh2(aa, bb);
    }
    __syncthreads();
  }
}

// ---------- k_gemm: 256x256 8-wave, double-buffered LDS, counted vmcnt ----------
#define GSTAGE(KT, C) { _Pragma("unroll") \
  for (int j5 = 0; j5 < 4; ++j5) { \
    int c4 = tid + j5 * 512; \
    int r5 = c4 >> 3, c16 = c4 & 7; \
    int sk = c16 ^ (r5 & 7); \
    gload16(Abase + (size_t)r5 * KX + (KT) * 64 + sk * 8, (char*)Ah[C] + c4 * 16); \
  } \
  _Pragma("unroll") \
  for (int j5 = 0; j5 < 4; ++j5) { \
    int c4 = tid + j5 * 512; \
    int r5 = c4 >> 3, c16 = c4 & 7; \
    int sk = c16 ^ (r5 & 7); \
    gload16(Bbase + (size_t)r5 * KX + (KT) * 64 + sk * 8, (char*)Bh[C] + c4 * 16); \
  } }

__global__ __launch_bounds__(512) void k_gemm(
    const unsigned short* __restrict__ Xb,
    const unsigned short* __restrict__ WoT,
    const float* __restrict__ bout,
    float* __restrict__ out)
{
  __shared__ __align__(16) unsigned short Ah[2][256 * 64];
  __shared__ __align__(16) unsigned short Bh[2][256 * 64];
  int bid = blockIdx.x;
  int swz = (bid & 7) * 128 + (bid >> 3);
  int by = swz >> 5, bx = swz & 31;
  int tid = threadIdx.x;
  int lane = tid & 63;
  int wid = tid >> 6;
  int wrow = wid >> 2, wcol = wid & 3;

  const unsigned short* Abase = Xb + (size_t)by * 256 * KX;
  const unsigned short* Bbase = WoT + (size_t)bx * 256 * KX;

  f32x4 acc[8][4];
  #pragma unroll
  for (int i = 0; i < 8; ++i)
    #pragma unroll
    for (int j = 0; j < 4; ++j) acc[i][j] = (f32x4)0.f;

  GSTAGE(0, 0)
  GSTAGE(1, 1)
  asm volatile("s_waitcnt vmcnt(8)" ::: "memory");
  __builtin_amdgcn_s_barrier();
  __builtin_amdgcn_sched_barrier(0);

  for (int kt = 0; kt < 20; ++kt) {
    int c = kt & 1;
    const char* Ab = (const char*)Ah[c];
    const char* Bb = (const char*)Bh[c];
    short8 af[4][2], bf[4][2];
    #pragma unroll
    for (int i = 0; i < 4; ++i)
      #pragma unroll
      for (int ks = 0; ks < 2; ++ks) {
        int rw = wrow * 128 + i * 16 + (lane & 15);
        int kc = ks * 4 + (lane >> 4);
        af[i][ks] = *(const short8*)(Ab + rw * 128 + ((kc ^ (rw & 7)) * 16));
      }
    #pragma unroll
    for (int j = 0; j < 4; ++j)
      #pragma unroll
      for (int ks = 0; ks < 2; ++ks) {
        int rb = wcol * 64 + j * 16 + (lane & 15);
        int kc = ks * 4 + (lane >> 4);
        bf[j][ks] = *(const short8*)(Bb + rb * 128 + ((kc ^ (rb & 7)) * 16));
      }
    __builtin_amdgcn_s_setprio(1);
    #pragma unroll
    for (int i = 0; i < 4; ++i)
      #pragma unroll
      for (int j = 0; j < 4; ++j)
        #pragma unroll
        for (int ks = 0; ks < 2; ++ks)
          acc[i][j] = __builtin_amdgcn_mfma_f32_16x16x32_bf16(af[i][ks], bf[j][ks], acc[i][j], 0, 0, 0);
    __builtin_amdgcn_s_setprio(0);
    #pragma unroll
    for (int i = 0; i < 4; ++i)
      #pragma unroll
      for (int ks = 0; ks < 2; ++ks) {
        int rw = wrow * 128 + 64 + i * 16 + (lane & 15);
        int kc = ks * 4 + (lane >> 4);
        af[i][ks] = *(const short8*)(Ab + rw * 128 + ((kc ^ (rw & 7)) * 16));
      }
    __builtin_amdgcn_s_setprio(1);
    #pragma unroll
    for (int i = 0; i < 4; ++i)
      #pragma unroll
      for (int j = 0; j < 2; ++j)
        #pragma unroll
        for (int ks = 0; ks < 2; ++ks)
          acc[4 + i][j] = __builtin_amdgcn_mfma_f32_16x16x32_bf16(af[i][ks], bf[j][ks], acc[4 + i][j], 0, 0, 0);
    __builtin_amdgcn_s_setprio(0);
    __builtin_amdgcn_s_barrier();
    __builtin_amdgcn_sched_barrier(0);
    if (kt < 18) GSTAGE(kt + 2, c)
    __builtin_amdgcn_s_setprio(1);
    #pragma unroll
    for (int i = 0; i < 4; ++i)
      #pragma unroll
      for (int j = 0; j < 2; ++j)
        #pragma unroll
        for (int ks = 0; ks < 2; ++ks)
          acc[4 + i][2 + j] = __builtin_amdgcn_mfma_f32_16x16x32_bf16(af[i][ks], bf[2 + j][ks], acc[4 + i][2 + j], 0, 0, 0);
    __builtin_amdgcn_s_setprio(0);
    if (kt < 18) { asm volatile("s_waitcnt vmcnt(8)" ::: "memory"); }
    else         { asm volatile("s_waitcnt vmcnt(0)" ::: "memory"); }
    __builtin_amdgcn_s_barrier();
    __builtin_amdgcn_sched_barrier(0);
  }

  int rl = lane >> 4, cl = lane & 15;
  #pragma unroll
  for (int j = 0; j < 4; ++j) {
    int gn = bx * 256 + wcol * 64 + j * 16 + cl;
    if (gn >= VOC) continue;
    float bv = bout[gn];
    #pragma unroll
    for (int i = 0; i < 8; ++i) {
      #pragma unroll
      for (int q = 0; q < 4; ++q) {
        int gm = by * 256 + wrow * 128 + i * 16 + rl * 4 + q;
        int tt = gm >> 6, bb = gm & 63;
        float v = acc[i][j][q] + bv;
        v = v > 0.f ? v : (expf(v) - 1.f);
        out[((size_t)bb * TLEN + tt) * VOC + gn] = v;
      }
    }
  }
}

// ---------- launch ----------
extern "C" void kernel_launch(void* const* d_in, const int* in_sizes, int n_in,
                              void* d_out, int out_size, void* d_ws, size_t ws_size,
                              hipStream_t stream) {
  const float* enc  = (const float*)d_in[0];
  const int*   ro   = (const int*)d_in[1];
  const float* We1  = (const float*)d_in[2];
  const float* be1  = (const float*)d_in[3];
  const float* We2  = (const float*)d_in[4];
  const float* be2  = (const float*)d_in[5];
  const float* emb  = (const float*)d_in[6];
  const float* Wr   = (const float*)d_in[7];
  const float* brnn = (const float*)d_in[8];
  const float* Wo   = (const float*)d_in[9];
  const float* bo   = (const float*)d_in[10];

  char* ws = (char*)d_ws;
  unsigned short* X     = (unsigned short*)(ws);                 // 20,971,520
  unsigned short* WoT   = (unsigned short*)(ws + 20971520);      // 20,971,520 (8192 rows)
  unsigned short* W2    = (unsigned short*)(ws + 41943040);      //    524,288
  unsigned short* WembT = (unsigned short*)(ws + 42467328);      //    262,144
  unsigned short* WctxT = (unsigned short*)(ws + 42729472);      //    524,288
  unsigned short* ench  = (unsigned short*)(ws + 43253760);      //  8,388,608 (reused: encTh)
  float*          E1    = (float*)(ws + 51642368);               //    655,360
  unsigned short* Remb  = (unsigned short*)(ws + 52297728);      //  8,388,608 (reused: wh)
  unsigned short* encW2 = (unsigned short*)(ws + 60686336);      //  8,388,608
  unsigned short* encTh = ench;
  unsigned short* wh    = Remb;

  float* outs = (float*)d_out;
  float* wout = (float*)d_out + (size_t)BATCH * TLEN * VOC;

  k_pre1 <<<dim3(14336),    256, 0, stream>>>(ro, emb, X, enc, ench, We1, E1);
  k_pre2 <<<dim3(1120),     256, 0, stream>>>(Wr, WembT, WctxT, W2);
  k_gs01 <<<dim3(4, 64, 2), 256, 0, stream>>>(X, WembT, ench, WctxT, brnn, Remb, encW2);
  k_recur<<<dim3(960),     1024, 0, stream>>>(We1, be1, We2, be2,
                                              (const uint4*)W2, (const uint4*)encW2,
                                              Remb, E1, X, wout,
                                              Wo, WoT, enc, encTh);
  k_wh   <<<dim3(1024),     256, 0, stream>>>(wout, wh);
  k_gs2  <<<dim3(4, 64),    256, 0, stream>>>(wh, encTh, brnn, X);
  k_gemm <<<dim3(1024),     512, 0, stream>>>(X, WoT, bo, outs);
  (void)in_sizes; (void)n_in; (void)out_size; (void)ws_size;
}

// Round 18
// 1177.358 us; speedup vs baseline: 1.1621x; 1.0009x over previous
//
#include <hip/hip_runtime.h>
#include <hip/hip_bf16.h>
#include <stdint.h>

#define BATCH 64
#define SLEN 128
#define TLEN 128
#define ENCD 512
#define DECD 512
#define EMBD 256
#define VOC  8000
#define HE   20
#define KX   1280      // EMB + DEC + ENC
#define NP2  8192      // VOC padded to 32*256

typedef __attribute__((ext_vector_type(8))) short short8;
typedef __attribute__((ext_vector_type(8))) _Float16 half8v;
typedef __attribute__((ext_vector_type(4))) float f32x4;
typedef _Float16 h2 __attribute__((ext_vector_type(2)));

// ---------- helpers ----------
__device__ inline unsigned short f2bf(float f) {
  union { float f; uint32_t u; } v; v.f = f;
  uint32_t r = v.u + 0x7fff + ((v.u >> 16) & 1);
  return (unsigned short)(r >> 16);
}
__device__ inline unsigned short f16bits(float f) {
  union { _Float16 h; unsigned short u; } c; c.h = (_Float16)f; return c.u;
}
__device__ inline uint32_t pkh2(float a, float b) {
  union { h2 h; uint32_t u; } v;
  v.h = h2{(_Float16)a, (_Float16)b};
  return v.u;
}
__device__ inline float fdot2(uint32_t a, uint32_t b, float c) {
#if __has_builtin(__builtin_amdgcn_fdot2)
  union { uint32_t u; h2 h; } x, y; x.u = a; y.u = b;
  return __builtin_amdgcn_fdot2(x.h, y.h, c, false);
#else
  union { uint32_t u; h2 h; } x, y; x.u = a; y.u = b;
  return c + (float)x.h[0] * (float)y.h[0] + (float)x.h[1] * (float)y.h[1];
#endif
}
__device__ inline float eluf(float x) { return x > 0.f ? x : (expf(x) - 1.f); }

typedef const __attribute__((address_space(1))) unsigned int* gptr_t;
typedef __attribute__((address_space(3))) unsigned int* lptr_t;
__device__ inline void gload16(const void* g, void* l) {
  __builtin_amdgcn_global_load_lds((gptr_t)g, (lptr_t)l, 16, 0, 0);
}

// ---------- k_pre1: merged k_lc / k_ench / k_e1 ----------
__global__ __launch_bounds__(256) void k_pre1(const int* __restrict__ ro,
                                              const float* __restrict__ emb,
                                              unsigned short* __restrict__ X,
                                              const float* __restrict__ enc,
                                              unsigned short* __restrict__ ench,
                                              const float* __restrict__ We1,
                                              float* __restrict__ E1) {
  __shared__ float rowbuf[4][ENCD];
  __shared__ float part[4][HE][2];
  int bid = blockIdx.x, tid = threadIdx.x;
  if (bid < 8192) {
    int r = bid;
    int t = r >> 6, b = r & 63;
    int lc = (t == 0) ? 0 : ro[b * TLEN + t - 1];
    lc = ((lc % VOC) + VOC) % VOC;
    X[(size_t)r * KX + tid] = f2bf(emb[(size_t)lc * EMBD + tid]);
  } else if (bid < 12288) {
    int i = ((bid - 8192) * 256 + tid) * 4;
    float4 v = *(const float4*)(enc + i);
    ushort4 o = { f16bits(v.x), f16bits(v.y), f16bits(v.z), f16bits(v.w) };
    *(ushort4*)(ench + i) = o;
  } else {
    int r0 = (bid - 12288) * 4;
    for (int i = tid; i < 4 * ENCD; i += 256) {
      int rl = i >> 9, e = i & 511;
      rowbuf[rl][e] = enc[(size_t)(r0 + rl) * ENCD + e];
    }
    __syncthreads();
    if (tid < 160) {
      int kg = tid / 80, rem = tid % 80, rl = rem / 20, h = rem % 20;
      float acc = 0.f;
      for (int k = kg * 256; k < kg * 256 + 256; ++k)
        acc += rowbuf[rl][k] * We1[k * HE + h];
      part[rl][h][kg] = acc;
    }
    __syncthreads();
    if (tid < 80) {
      int rl = tid / 20, h = tid % 20;
      int r = r0 + rl, bb = r >> 7, ss = r & 127;
      E1[((size_t)bb * HE + h) * SLEN + ss] = part[rl][h][0] + part[rl][h][1];
    }
  }
}

// ---------- k_pre2: merged k_tr_w(WembT) / k_tr_w(WctxT) / k_prep_wr ----------
__global__ __launch_bounds__(256) void k_pre2(const float* __restrict__ Wr,
                                              unsigned short* __restrict__ WembT,
                                              unsigned short* __restrict__ WctxT,
                                              unsigned short* __restrict__ W2) {
  __shared__ float tile[64][65];
  int bid = blockIdx.x, tid = threadIdx.x;
  if (bid < 96) {
    int k0, KN, fmt, bx, by;
    unsigned short* dst;
    if (bid < 32) { k0 = 0;   KN = 256; fmt = 1; bx = bid & 7; by = bid >> 3; dst = WembT; }
    else          { int id2 = bid - 32; k0 = 768; KN = 512; fmt = 0; bx = id2 & 7; by = id2 >> 3; dst = WctxT; }
    int n0 = bx * 64, kt = by * 64;
    for (int i = tid; i < 4096; i += 256) {
      int kk = i >> 6, nn = i & 63;
      tile[kk][nn] = Wr[(size_t)(k0 + kt + kk) * 512 + n0 + nn];
    }
    __syncthreads();
    for (int i = tid; i < 4096; i += 256) {
      int nn = i >> 6, kk = i & 63;
      float v = tile[kk][nn];
      dst[(size_t)(n0 + nn) * KN + kt + kk] = fmt ? f2bf(v) : f16bits(v);
    }
  } else {
    int i = (bid - 96) * 256 + tid;
    int n = i & 511;
    int j = (i >> 9) & 7;
    int kc = (i >> 12) & 31;
    int h = (i >> 17) & 1;
    int k = h * 256 + kc * 8 + j;
    W2[(((size_t)(h * 32 + kc) * 512) + n) * 8 + j] = f16bits(Wr[(size_t)(256 + k) * 512 + n]);
  }
}

// ---------- k_wh: wout f32 [8192][128] -> f16 ----------
__global__ __launch_bounds__(256) void k_wh(const float* __restrict__ wout,
                                            unsigned short* __restrict__ wh) {
  int i = (blockIdx.x * 256 + threadIdx.x) * 4;
  float4 v = *(const float4*)(wout + i);
  ushort4 o = { f16bits(v.x), f16bits(v.y), f16bits(v.z), f16bits(v.w) };
  *(ushort4*)(wh + i) = o;
}

// ---------- gs_body<MODE>: 128x128xK MFMA GEMM body ----------
#define BM 128
#define BN 128
#define BK 64

template<int MODE>
__device__ __forceinline__ void gs_body(
    unsigned short* Asd, unsigned short* Bsd,
    const unsigned short* __restrict__ A,
    const unsigned short* __restrict__ B,
    const float* __restrict__ bias,
    unsigned short* __restrict__ Cout,
    int bx, int by, int tid)
{
  constexpr int As = (MODE == 0) ? KX : (MODE == 1 ? 512 : 128);
  constexpr int Bs = (MODE == 0) ? 256 : (MODE == 1 ? 512 : 128);
  constexpr int KT = (MODE == 0) ? 4 : (MODE == 1 ? 8 : 2);
  int wid = tid >> 6, lane = tid & 63;
  int wr = wid >> 1, wc = wid & 1;

  f32x4 acc[4][4];
  for (int i = 0; i < 4; ++i)
    for (int j = 0; j < 4; ++j) acc[i][j] = (f32x4)0.f;

  const unsigned short* Abase = A + (size_t)by * BM * As;
  const unsigned short* Bbase = B + (size_t)bx * BN * Bs + (MODE == 2 ? (size_t)by * 512 * 128 : 0);

  for (int kt = 0; kt < KT; ++kt) {
    for (int j = 0; j < 4; ++j) {
      int c = tid + j * 256;
      int r = c >> 3, c16 = c & 7;
      int sk = c16 ^ (r & 7);
      gload16(Abase + (size_t)r * As + kt * BK + sk * 8, (char*)Asd + c * 16);
      gload16(Bbase + (size_t)r * Bs + kt * BK + sk * 8, (char*)Bsd + c * 16);
    }
    __syncthreads();
    for (int ks = 0; ks < 2; ++ks) {
      short8 af[4], bf[4];
      int kc = ks * 4 + (lane >> 4);
      for (int i = 0; i < 4; ++i) {
        int r = wr * 64 + i * 16 + (lane & 15);
        af[i] = *(const short8*)((const char*)Asd + r * 128 + ((kc ^ (r & 7)) * 16));
      }
      for (int j = 0; j < 4; ++j) {
        int r = wc * 64 + j * 16 + (lane & 15);
        bf[j] = *(const short8*)((const char*)Bsd + r * 128 + ((kc ^ (r & 7)) * 16));
      }
      for (int i = 0; i < 4; ++i)
        for (int j = 0; j < 4; ++j) {
          if constexpr (MODE == 0)
            acc[i][j] = __builtin_amdgcn_mfma_f32_16x16x32_bf16(af[i], bf[j], acc[i][j], 0, 0, 0);
          else
            acc[i][j] = __builtin_amdgcn_mfma_f32_16x16x32_f16(
                __builtin_bit_cast(half8v, af[i]), __builtin_bit_cast(half8v, bf[j]), acc[i][j], 0, 0, 0);
        }
    }
    __syncthreads();
  }

  int rl = lane >> 4, cl = lane & 15;
  for (int j = 0; j < 4; ++j) {
    int gn = bx * BN + wc * 64 + j * 16 + cl;
    for (int i = 0; i < 4; ++i) {
      for (int q = 0; q < 4; ++q) {
        int gm = by * BM + wr * 64 + i * 16 + rl * 4 + q;
        float v = acc[i][j][q];
        if constexpr (MODE == 0) {
          Cout[(size_t)gm * 512 + gn] = f16bits(v + bias[gn]);
        } else if constexpr (MODE == 1) {
          int bb = gm >> 7, s = gm & 127;
          Cout[(((size_t)(bb * 16 + (s >> 3)) * 512) + gn) * 8 + (s & 7)] = f16bits(v);
        } else {
          int tt = gm & 127, bb = gm >> 7;
          Cout[((size_t)tt * 64 + bb) * KX + 768 + gn] = f2bf(v);
        }
      }
    }
  }
}

// ---------- k_gs01: MODE0 (z=0) and MODE1 (z=1) in one launch ----------
__global__ __launch_bounds__(256) void k_gs01(
    const unsigned short* __restrict__ X,
    const unsigned short* __restrict__ WembT,
    const unsigned short* __restrict__ ench,
    const unsigned short* __restrict__ WctxT,
    const float* __restrict__ brnn,
    unsigned short* __restrict__ Remb,
    unsigned short* __restrict__ encW2)
{
  __shared__ __align__(16) unsigned short Asd[BM * BK];
  __shared__ __align__(16) unsigned short Bsd[BN * BK];
  if (blockIdx.z == 0)
    gs_body<0>(Asd, Bsd, X, WembT, brnn, Remb, blockIdx.x, blockIdx.y, threadIdx.x);
  else
    gs_body<1>(Asd, Bsd, ench, WctxT, brnn, encW2, blockIdx.x, blockIdx.y, threadIdx.x);
}

// ---------- k_gs2: MODE2 (ctx fill) ----------
__global__ __launch_bounds__(256) void k_gs2(
    const unsigned short* __restrict__ wh,
    const unsigned short* __restrict__ encTh,
    const float* __restrict__ brnn,
    unsigned short* __restrict__ X)
{
  __shared__ __align__(16) unsigned short Asd[BM * BK];
  __shared__ __align__(16) unsigned short Bsd[BN * BK];
  gs_body<2>(Asd, Bsd, wh, encTh, brnn, X, blockIdx.x, blockIdx.y, threadIdx.x);
}

// ---------- k_recur: r10/r14 recurrence (blocks 0..63) + independent transposes ----------
// blocks 64..703 : W_out -> WoT [8192][1280] bf16 (zero-pad, 4 tiles each)
// blocks 704..959: enc -> encTh [b][e][s] f16 (4 tiles each)
#define STREAM4(PH) { \
  float a0 = 0, a1 = 0, a2 = 0, a3 = 0; \
  uint4 cb[8], nb[8]; \
  _Pragma("unroll") \
  for (int j = 0; j < 8; ++j) cb[j] = Wp[(size_t)j * 512]; \
  for (int blk = 0; blk < 4; ++blk) { \
    if (blk + 1 < 4) { \
      _Pragma("unroll") \
      for (int j = 0; j < 8; ++j) nb[j] = Wp[(size_t)((blk + 1) * 8 + j) * 512]; \
    } \
    _Pragma("unroll") \
    for (int j = 0; j < 8; ++j) { \
      uint4 wv = cb[j]; uint4 xv = hp4[hbase + blk * 8 + j]; \
      a0 = fdot2(wv.x, xv.x, a0); a1 = fdot2(wv.y, xv.y, a1); \
      a2 = fdot2(wv.z, xv.z, a2); a3 = fdot2(wv.w, xv.w, a3); \
    } \
    _Pragma("unroll") \
    for (int j = 0; j < 8; ++j) cb[j] = nb[j]; \
  } \
  ph[PH][mn] = (a0 + a1) + (a2 + a3); }

__global__ __launch_bounds__(1024) void k_recur(
    const float* __restrict__ We1,
    const float* __restrict__ be1,
    const float* __restrict__ We2,
    const float* __restrict__ be2,
    const uint4* __restrict__ W2,
    const uint4* __restrict__ encW2,
    const unsigned short* __restrict__ Remb,
    const float* __restrict__ E1g,
    unsigned short* __restrict__ X,
    float* __restrict__ wout,
    const float* __restrict__ Wo,
    unsigned short* __restrict__ WoT,
    const float* __restrict__ enc,
    unsigned short* __restrict__ encTh)
{
  __shared__ __align__(16) uint4 el[16][512];
  __shared__ uint32_t E1p[HE][SLEN / 2];
  __shared__ uint32_t w1p[HE][257];
  __shared__ uint32_t hpair[DECD / 2];
  __shared__ uint32_t wpairS[SLEN / 2];
  __shared__ float ph[2][DECD];
  __shared__ float be1s[HE], w2s[HE];
  __shared__ float be2s;

  int bid = blockIdx.x, tid = threadIdx.x;

  if (bid >= 64) {
    float (*tile)[65] = (float(*)[65])el;
    if (bid < 704) {
      for (int q = 0; q < 4; ++q) {
        int t4 = (bid - 64) * 4 + q;
        int n0 = (t4 % 128) * 64, k0 = (t4 / 128) * 64;
        for (int i = tid; i < 4096; i += 1024) {
          int kk = i >> 6, nn = i & 63;
          int n = n0 + nn;
          tile[kk][nn] = (n < VOC) ? Wo[(size_t)(k0 + kk) * VOC + n] : 0.f;
        }
        __syncthreads();
        for (int i = tid; i < 4096; i += 1024) {
          int nn = i >> 6, kk = i & 63;
          WoT[(size_t)(n0 + nn) * KX + k0 + kk] = f2bf(tile[kk][nn]);
        }
        __syncthreads();
      }
    } else {
      for (int q = 0; q < 4; ++q) {
        int t4 = (bid - 704) * 4 + q;
        int eb_ = t4 >> 4;
        int e0 = ((t4 >> 1) & 7) * 64;
        int s0 = (t4 & 1) * 64;
        const float* ebp = enc + (size_t)eb_ * SLEN * ENCD;
        for (int i = tid; i < 4096; i += 1024) {
          int ss = i >> 6, ee = i & 63;
          tile[ss][ee] = ebp[(size_t)(s0 + ss) * ENCD + e0 + ee];
        }
        __syncthreads();
        unsigned short* ob = encTh + (size_t)eb_ * ENCD * SLEN;
        for (int i = tid; i < 4096; i += 1024) {
          int ee = i >> 6, ss = i & 63;
          ob[(size_t)(e0 + ee) * SLEN + s0 + ss] = f16bits(tile[ss][ee]);
        }
        __syncthreads();
      }
    }
    return;
  }

  int b = bid;

  for (int i = tid; i < 16 * 512; i += 1024) ((uint4*)el)[i] = encW2[(size_t)b * 8192 + i];
  for (int i = tid; i < HE * (SLEN / 2); i += 1024) {
    int h = i >> 6, p = i & 63;
    const float* ebase = E1g + ((size_t)b * HE + h) * SLEN;
    ((uint32_t*)E1p)[i] = pkh2(ebase[2 * p], ebase[2 * p + 1]);
  }
  for (int i = tid; i < HE * 256; i += 1024) {
    int h = i >> 8, p = i & 255;
    w1p[h][p] = pkh2(We1[(size_t)(ENCD + 2 * p) * HE + h],
                     We1[(size_t)(ENCD + 2 * p + 1) * HE + h]);
  }
  for (int i = tid; i < DECD / 2; i += 1024) hpair[i] = 0;
  for (int i = tid; i < DECD; i += 1024) { ph[0][i] = 0.f; ph[1][i] = 0.f; }
  if (tid < HE) { be1s[tid] = be1[tid]; w2s[tid] = We2[tid]; }
  if (tid == 0) be2s = be2[0];
  __syncthreads();

  const int lane = tid & 63;
  const int wv_ = tid >> 6;
  int mn, mh0;
  if (tid < 448)      { mn = tid;        mh0 = 0; }
  else if (tid < 896) { mn = tid - 448;  mh0 = 1; }
  else if (tid < 960) { mn = 448 + lane; mh0 = 0; }
  else                { mn = 448 + lane; mh0 = 1; }
  const uint4* Wp = W2 + (size_t)(mh0 * 32) * 512 + mn;
  const uint4* hp4 = (const uint4*)hpair;
  const int hbase = mh0 * 32;

  int ah = lane % 20, aseg = lane / 20;
  int q0 = aseg * 86;
  int q1 = (aseg == 2) ? 256 : q0 + 86;
  if (aseg >= 3) { q0 = 0; q1 = 0; }

  for (int t = 0; t < TLEN; ++t) {
    const int rowr = t * BATCH + b;
    float rpre = 0.f;

    if (wv_ < 15) {
      if (tid < 512) {
        union { unsigned short u; _Float16 f; } c;
        c.u = Remb[(size_t)rowr * 512 + tid];
        rpre = (float)c.f;
      }
      STREAM4(mh0)
    } else {
      __builtin_amdgcn_s_setprio(1);
      float p0 = 0, p1 = 0;
      for (int q = q0; q < q1; q += 2) {
        p0 = fdot2(w1p[ah][q], hpair[q], p0);
        p1 = fdot2(w1p[ah][q + 1], hpair[q + 1], p1);
      }
      float p = p0 + p1;
      float pa = __shfl(p, lane + 20);
      float pb = __shfl(p, lane + 40);
      float edv = p + pa + pb + ((lane < HE) ? be1s[lane] : 0.f);
      float e0a = 0.f, e1a = 0.f;
      #pragma unroll
      for (int h = 0; h < HE; ++h) {
        union { uint32_t u; h2 hh; } e; e.u = E1p[h][lane];
        float ed = __shfl(edv, h);
        e0a += eluf((float)e.hh[0] + ed) * w2s[h];
        e1a += eluf((float)e.hh[1] + ed) * w2s[h];
      }
      float s0 = expf(eluf(e0a + be2s));
      float s1 = expf(eluf(e1a + be2s));
      float tot = s0 + s1;
      #pragma unroll
      for (int o = 1; o < 64; o <<= 1) tot += __shfl_xor(tot, o);
      float inv = 1.f / tot;
      float w0 = s0 * inv, w1 = s1 * inv;
      wpairS[lane] = pkh2(w0, w1);
      float2 wv2 = { w0, w1 };
      *(float2*)(wout + ((size_t)b * TLEN + t) * SLEN + 2 * lane) = wv2;
      __builtin_amdgcn_s_setprio(0);
      STREAM4(1)
    }
    __syncthreads();

    if (tid < 512) {
      int n = tid;
      float c0 = 0, c1 = 0, c2 = 0, c3 = 0;
      #pragma unroll
      for (int g = 0; g < 16; ++g) {
        uint4 ev = el[g][n];
        uint4 wv = ((const uint4*)wpairS)[g];
        c0 = fdot2(ev.x, wv.x, c0); c1 = fdot2(ev.y, wv.y, c1);
        c2 = fdot2(ev.z, wv.z, c2); c3 = fdot2(ev.w, wv.w, c3);
      }
      float v = rpre + ph[0][n] + ph[1][n] + (c0 + c1) + (c2 + c3);
      float aa = eluf(v);
      X[(size_t)rowr * KX + 256 + n] = f2bf(aa);
      float bb = __shfl_down(aa, 1);
      if (!(n & 1)) hpair[n >> 1] = pkh2(aa, bb);
    }
    __syncthreads();
  }
}

// ---------- k_gemm: 256x256 8-wave, double-buffered LDS, counted vmcnt ----------
#define GSTAGE(KT, C) { _Pragma("unroll") \
  for (int j5 = 0; j5 < 4; ++j5) { \
    int c4 = tid + j5 * 512; \
    int r5 = c4 >> 3, c16 = c4 & 7; \
    int sk = c16 ^ (r5 & 7); \
    gload16(Abase + (size_t)r5 * KX + (KT) * 64 + sk * 8, (char*)Ah[C] + c4 * 16); \
  } \
  _Pragma("unroll") \
  for (int j5 = 0; j5 < 4; ++j5) { \
    int c4 = tid + j5 * 512; \
    int r5 = c4 >> 3, c16 = c4 & 7; \
    int sk = c16 ^ (r5 & 7); \
    gload16(Bbase + (size_t)r5 * KX + (KT) * 64 + sk * 8, (char*)Bh[C] + c4 * 16); \
  } }

__global__ __launch_bounds__(512) void k_gemm(
    const unsigned short* __restrict__ Xb,
    const unsigned short* __restrict__ WoT,
    const float* __restrict__ bout,
    float* __restrict__ out)
{
  __shared__ __align__(16) unsigned short Ah[2][256 * 64];
  __shared__ __align__(16) unsigned short Bh[2][256 * 64];
  int bid = blockIdx.x;
  int swz = (bid & 7) * 128 + (bid >> 3);
  int by = swz >> 5, bx = swz & 31;
  int tid = threadIdx.x;
  int lane = tid & 63;
  int wid = tid >> 6;
  int wrow = wid >> 2, wcol = wid & 3;

  const unsigned short* Abase = Xb + (size_t)by * 256 * KX;
  const unsigned short* Bbase = WoT + (size_t)bx * 256 * KX;

  f32x4 acc[8][4];
  #pragma unroll
  for (int i = 0; i < 8; ++i)
    #pragma unroll
    for (int j = 0; j < 4; ++j) acc[i][j] = (f32x4)0.f;

  GSTAGE(0, 0)
  GSTAGE(1, 1)
  asm volatile("s_waitcnt vmcnt(8)" ::: "memory");
  __builtin_amdgcn_s_barrier();
  __builtin_amdgcn_sched_barrier(0);

  for (int kt = 0; kt < 20; ++kt) {
    int c = kt & 1;
    const char* Ab = (const char*)Ah[c];
    const char* Bb = (const char*)Bh[c];
    short8 af[4][2], bf[4][2];
    #pragma unroll
    for (int i = 0; i < 4; ++i)
      #pragma unroll
      for (int ks = 0; ks < 2; ++ks) {
        int rw = wrow * 128 + i * 16 + (lane & 15);
        int kc = ks * 4 + (lane >> 4);
        af[i][ks] = *(const short8*)(Ab + rw * 128 + ((kc ^ (rw & 7)) * 16));
      }
    #pragma unroll
    for (int j = 0; j < 4; ++j)
      #pragma unroll
      for (int ks = 0; ks < 2; ++ks) {
        int rb = wcol * 64 + j * 16 + (lane & 15);
        int kc = ks * 4 + (lane >> 4);
        bf[j][ks] = *(const short8*)(Bb + rb * 128 + ((kc ^ (rb & 7)) * 16));
      }
    __builtin_amdgcn_s_setprio(1);
    #pragma unroll
    for (int i = 0; i < 4; ++i)
      #pragma unroll
      for (int j = 0; j < 4; ++j)
        #pragma unroll
        for (int ks = 0; ks < 2; ++ks)
          acc[i][j] = __builtin_amdgcn_mfma_f32_16x16x32_bf16(af[i][ks], bf[j][ks], acc[i][j], 0, 0, 0);
    __builtin_amdgcn_s_setprio(0);
    #pragma unroll
    for (int i = 0; i < 4; ++i)
      #pragma unroll
      for (int ks = 0; ks < 2; ++ks) {
        int rw = wrow * 128 + 64 + i * 16 + (lane & 15);
        int kc = ks * 4 + (lane >> 4);
        af[i][ks] = *(const short8*)(Ab + rw * 128 + ((kc ^ (rw & 7)) * 16));
      }
    __builtin_amdgcn_s_setprio(1);
    #pragma unroll
    for (int i = 0; i < 4; ++i)
      #pragma unroll
      for (int j = 0; j < 2; ++j)
        #pragma unroll
        for (int ks = 0; ks < 2; ++ks)
          acc[4 + i][j] = __builtin_amdgcn_mfma_f32_16x16x32_bf16(af[i][ks], bf[j][ks], acc[4 + i][j], 0, 0, 0);
    __builtin_amdgcn_s_setprio(0);
    __builtin_amdgcn_s_barrier();
    __builtin_amdgcn_sched_barrier(0);
    if (kt < 18) GSTAGE(kt + 2, c)
    __builtin_amdgcn_s_setprio(1);
    #pragma unroll
    for (int i = 0; i < 4; ++i)
      #pragma unroll
      for (int j = 0; j < 2; ++j)
        #pragma unroll
        for (int ks = 0; ks < 2; ++ks)
          acc[4 + i][2 + j] = __builtin_amdgcn_mfma_f32_16x16x32_bf16(af[i][ks], bf[2 + j][ks], acc[4 + i][2 + j], 0, 0, 0);
    __builtin_amdgcn_s_setprio(0);
    if (kt < 18) { asm volatile("s_waitcnt vmcnt(8)" ::: "memory"); }
    else         { asm volatile("s_waitcnt vmcnt(0)" ::: "memory"); }
    __builtin_amdgcn_s_barrier();
    __builtin_amdgcn_sched_barrier(0);
  }

  int rl = lane >> 4, cl = lane & 15;
  #pragma unroll
  for (int j = 0; j < 4; ++j) {
    int gn = bx * 256 + wcol * 64 + j * 16 + cl;
    if (gn >= VOC) continue;
    float bv = bout[gn];
    #pragma unroll
    for (int i = 0; i < 8; ++i) {
      #pragma unroll
      for (int q = 0; q < 4; ++q) {
        int gm = by * 256 + wrow * 128 + i * 16 + rl * 4 + q;
        int tt = gm >> 6, bb = gm & 63;
        float v = acc[i][j][q] + bv;
        v = v > 0.f ? v : (expf(v) - 1.f);
        out[((size_t)bb * TLEN + tt) * VOC + gn] = v;
      }
    }
  }
}

// ---------- launch ----------
extern "C" void kernel_launch(void* const* d_in, const int* in_sizes, int n_in,
                              void* d_out, int out_size, void* d_ws, size_t ws_size,
                              hipStream_t stream) {
  const float* enc  = (const float*)d_in[0];
  const int*   ro   = (const int*)d_in[1];
  const float* We1  = (const float*)d_in[2];
  const float* be1  = (const float*)d_in[3];
  const float* We2  = (const float*)d_in[4];
  const float* be2  = (const float*)d_in[5];
  const float* emb  = (const float*)d_in[6];
  const float* Wr   = (const float*)d_in[7];
  const float* brnn = (const float*)d_in[8];
  const float* Wo   = (const float*)d_in[9];
  const float* bo   = (const float*)d_in[10];

  char* ws = (char*)d_ws;
  unsigned short* X     = (unsigned short*)(ws);                 // 20,971,520
  unsigned short* WoT   = (unsigned short*)(ws + 20971520);      // 20,971,520 (8192 rows)
  unsigned short* W2    = (unsigned short*)(ws + 41943040);      //    524,288
  unsigned short* WembT = (unsigned short*)(ws + 42467328);      //    262,144
  unsigned short* WctxT = (unsigned short*)(ws + 42729472);      //    524,288
  unsigned short* ench  = (unsigned short*)(ws + 43253760);      //  8,388,608 (reused: encTh)
  float*          E1    = (float*)(ws + 51642368);               //    655,360
  unsigned short* Remb  = (unsigned short*)(ws + 52297728);      //  8,388,608 (reused: wh)
  unsigned short* encW2 = (unsigned short*)(ws + 60686336);      //  8,388,608
  unsigned short* encTh = ench;
  unsigned short* wh    = Remb;

  float* outs = (float*)d_out;
  float* wout = (float*)d_out + (size_t)BATCH * TLEN * VOC;

  k_pre1 <<<dim3(14336),    256, 0, stream>>>(ro, emb, X, enc, ench, We1, E1);
  k_pre2 <<<dim3(1120),     256, 0, stream>>>(Wr, WembT, WctxT, W2);
  k_gs01 <<<dim3(4, 64, 2), 256, 0, stream>>>(X, WembT, ench, WctxT, brnn, Remb, encW2);
  k_recur<<<dim3(960),     1024, 0, stream>>>(We1, be1, We2, be2,
                                              (const uint4*)W2, (const uint4*)encW2,
                                              Remb, E1, X, wout,
                                              Wo, WoT, enc, encTh);
  k_wh   <<<dim3(1024),     256, 0, stream>>>(wout, wh);
  k_gs2  <<<dim3(4, 64),    256, 0, stream>>>(wh, encTh, brnn, X);
  k_gemm <<<dim3(1024),     512, 0, stream>>>(X, WoT, bo, outs);
  (void)in_sizes; (void)n_in; (void)out_size; (void)ws_size;
}